// Round 5
// baseline (467.050 us; speedup 1.0000x reference)
//
#include <hip/hip_runtime.h>

#define B_TOT 4096
#define T_STEPS 512
#define IN 20
#define HID 51

typedef float f32x4 __attribute__((ext_vector_type(4)));
typedef short s16x8 __attribute__((ext_vector_type(8)));

__device__ __forceinline__ unsigned short f2bf(float f) {
    unsigned int u = __float_as_uint(f);
    unsigned int r = (u + 0x7fffu + ((u >> 16) & 1u)) >> 16;
    return (unsigned short)r;
}

#define L2E  1.4426950408889634f
#define L2E2 2.8853900817779268f

__device__ __forceinline__ float fast_rcp(float x) { return __builtin_amdgcn_rcpf(x); }
__device__ __forceinline__ float ex2(float x)      { return __builtin_amdgcn_exp2f(x); }
// sigma(x) where p = -x*log2(e) was folded into the weights
__device__ __forceinline__ float sig_p(float p)  { return fast_rcp(1.0f + ex2(p)); }
// tanh(x) where q = 2x*log2(e) was folded into the weights
__device__ __forceinline__ float tanh_q(float q) { return 1.0f - 2.0f * fast_rcp(1.0f + ex2(q)); }
// L2E2 * tanh(x), same folded argument — keeps cell state pre-scaled (C = L2E2*c)
__device__ __forceinline__ float tanh2_q(float q) {
    return __builtin_fmaf(fast_rcp(1.0f + ex2(q)), -2.0f * L2E2, L2E2);
}

// 8 waves, 16 batches/block, grid = 256 (1 chain/CU).
// Straggler surgery (r5): the L2 wave's serial scalar chain (dependent
// trans ops) used to sit between its MFMA and the barrier every step. Now:
//  - w6 owns ONLY the L2 tile: per step it does 2 MFMAs and saves the gate
//    vector; the dependent nonlinear chain is DEFERRED to the top of the next
//    step, where it overlaps the LDS-read latency of the next burst.
//  - x quad-buffer + accx precompute (r4): stager writes x_{t+2} / loads
//    x_{t+4} at the top of step t (no vmcnt drain at the barrier); every tile
//    wave computes the x-chunk MFMA for step t+1 at the bottom of step t.
//   w0: L1 tile {0}      + x stager (5 elems/lane, register-pipelined)
//   w1..w5: L1 tiles {1..10} (2 each)
//   w6: L2 tile only (rows 0..3 = Wih2 gates; K-chunks 1,2), chain deferred
//   w7: L1 tiles {11,12}
// Weights/biases pre-scaled by -log2e (i,f,o) / 2*log2e (g); cell state kept
// as C = 2*log2e*c so tanh_q(C) needs no mul in the dependent chain.

__global__ __launch_bounds__(512, 2)
void lstm_fused(const float* __restrict__ x,
                const float* __restrict__ Wih1, const float* __restrict__ Whh1,
                const float* __restrict__ bih1, const float* __restrict__ bhh1,
                const float* __restrict__ Wih2, const float* __restrict__ Whh2,
                const float* __restrict__ bih2, const float* __restrict__ bhh2,
                const float* __restrict__ Wmu,  const float* __restrict__ bmu,
                const float* __restrict__ Wlv,  const float* __restrict__ blv,
                float* __restrict__ out)
{
    // h staging: [buf][chunk(c=0:k32..63,c=1:k64..95)][(((k>>3)&3)<<4)|batch][k&7]
    __shared__ __align__(16) unsigned short vA[2][2][64][8];
    // x staging, quad-buffered: slot t%4 holds x_t fragments (rows 48..63 stay 0)
    __shared__ __align__(16) unsigned short xS[4][64][8];

    const int tid  = threadIdx.x;
    const int lane = tid & 63;
    const int w    = tid >> 6;      // 0..7
    const int bidx = blockIdx.x;

    const int tbase = (w == 0) ? 0 : (w == 7) ? 11 : (w == 6) ? 0 : 2 * w - 1;
    const int ntile = (w == 0) ? 1 : (w == 6) ? 0 : 2;
    const bool isST = (w == 0);     // x stager
    const bool isL2 = (w == 6);     // dedicated layer-2 wave

    // ---- gather A-operand weight fragments: A[m=lane&15][k=(lane>>4)*8+j] ----
    s16x8 wfrag[2][3];
    f32x4 binit[2];
    #pragma unroll
    for (int ti = 0; ti < 2; ++ti) {
        const int tau = tbase + ti;
        const int m = lane & 15;
        const bool act = (ti < ntile);
        #pragma unroll
        for (int ks = 0; ks < 3; ++ks) {
            s16x8 f;
            #pragma unroll
            for (int j = 0; j < 8; ++j) {
                int k = ks * 32 + ((lane >> 4) << 3) + j;
                float v = 0.0f;
                if (act) {
                    int g = m & 3, unit = tau * 4 + (m >> 2);
                    if (unit < HID) {
                        int row = g * HID + unit;
                        if (k < IN) v = Wih1[row * IN + k];
                        else if (k >= 32 && k < 32 + HID) v = Whh1[row * HID + (k - 32)];
                        v *= (g == 2) ? L2E2 : -L2E;
                    }
                }
                f[j] = (short)f2bf(v);
            }
            wfrag[ti][ks] = f;
        }
        f32x4 bi = {0.f, 0.f, 0.f, 0.f};
        if (act) {
            int unit = tau * 4 + (lane >> 4);
            if (unit < HID) {
                #pragma unroll
                for (int r = 0; r < 4; ++r)
                    bi[r] = (bih1[r * HID + unit] + bhh1[r * HID + unit]) * ((r == 2) ? L2E2 : -L2E);
            }
        }
        binit[ti] = bi;
    }

    // ---- layer-2 tile fragments (w6 only): rows 0..3 = Wih2 gates, chunks 1,2 ----
    s16x8 l2frag[2];
    f32x4 l2binit = {0.f, 0.f, 0.f, 0.f};
    float whh2g[4] = {0.f, 0.f, 0.f, 0.f};
    if (isL2) {
        const int m = lane & 15;
        #pragma unroll
        for (int ks = 1; ks < 3; ++ks) {
            s16x8 f;
            #pragma unroll
            for (int j = 0; j < 8; ++j) {
                int k = ks * 32 + ((lane >> 4) << 3) + j;
                float v = 0.0f;
                if (m < 4 && k >= 32 && k < 32 + HID)
                    v = Wih2[m * HID + (k - 32)] * ((m == 2) ? L2E2 : -L2E);
                f[j] = (short)f2bf(v);
            }
            l2frag[ks - 1] = f;
        }
        #pragma unroll
        for (int r = 0; r < 4; ++r) {
            float s = (r == 2) ? L2E2 : -L2E;
            whh2g[r]   = Whh2[r] * s;
            l2binit[r] = (bih2[r] + bhh2[r]) * s;
        }
    }

    // ---- x stager setup (w0): 5 elems/lane, e = i*64+lane (320 total, no mask) ----
    const float* sp[5];
    int srow[5], sj[5];
    if (isST) {
        #pragma unroll
        for (int i = 0; i < 5; ++i) {
            int e = i * 64 + lane;
            int b = e / IN, m = e % IN;
            sp[i]   = x + ((size_t)(bidx * 16 + b) * T_STEPS) * IN + m;
            srow[i] = ((m >> 3) & 3) * 16 + b;
            sj[i]   = m & 7;
        }
    }

    // ---- zero-init staging buffers (pads must stay exact 0 forever) ----
    {
        unsigned short* vz = &vA[0][0][0][0];
        for (int i = tid; i < 2 * 2 * 64 * 8; i += 512) vz[i] = 0;
        unsigned short* xz = &xS[0][0][0];
        for (int i = tid; i < 4 * 64 * 8; i += 512) xz[i] = 0;
    }
    __syncthreads();
    float rE[5], rO[5];
    if (isST) {
        #pragma unroll
        for (int i = 0; i < 5; ++i) {
            xS[0][srow[i]][sj[i]] = f2bf(sp[i][0]);          // x_0
            xS[1][srow[i]][sj[i]] = f2bf(sp[i][IN]);         // x_1
            rE[i] = sp[i][(size_t)2 * IN];                   // x_2 (write at t=0)
            rO[i] = sp[i][(size_t)3 * IN];                   // x_3 (write at t=1)
        }
    }
    __syncthreads();

    // ---- precompute accx (x-chunk MFMA) for step 0 from xS[0] ----
    f32x4 accx[2];
    {
        const s16x8 b00 = *(const s16x8*)&xS[0][lane][0];
        #pragma unroll
        for (int ti = 0; ti < 2; ++ti)
            if (ti < ntile)
                accx[ti] = __builtin_amdgcn_mfma_f32_16x16x32_bf16(wfrag[ti][0], b00, binit[ti], 0, 0, 0);
    }

    float C1[2] = {0.f, 0.f};       // pre-scaled cell state: C = 2*log2e*c
    float C2p = 0.f, h2p = 0.f, sum2 = 0.f;
    f32x4 aP = l2binit;             // deferred L2 gate vector (chain runs next step)

    // One timestep. P = tt&1 (h buffer), XR = (tt+1)%4 (x for next step),
    // XW = (tt+2)%4 (x slot written this step), XREG = rE (even tt) / rO (odd).
#define STEP(tt, P, XR, XW, XREG)                                                \
    {                                                                            \
        if (isST) {                                                              \
            const int t4 = ((tt) < T_STEPS - 4) ? (tt) + 4 : T_STEPS - 1;        \
            _Pragma("unroll")                                                    \
            for (int i = 0; i < 5; ++i) {                                        \
                xS[XW][srow[i]][sj[i]] = f2bf(XREG[i]);                          \
                XREG[i] = sp[i][(size_t)t4 * IN];                                \
            }                                                                    \
        }                                                                        \
        const s16x8 bf1 = *(const s16x8*)&vA[P][0][lane][0];                     \
        const s16x8 bf2 = *(const s16x8*)&vA[P][1][lane][0];                     \
        /* deferred L2 chain for step tt-1 (no LDS dep: overlaps read latency)*/ \
        if (isL2) {                                                              \
            if ((tt) >= 2 && lane < 16) {                                        \
                float pi = aP[0] + whh2g[0] * h2p;                               \
                float pf = aP[1] + whh2g[1] * h2p;                               \
                float pg = aP[2] + whh2g[2] * h2p;                               \
                float po = aP[3] + whh2g[3] * h2p;                               \
                float C2 = sig_p(pf) * C2p + sig_p(pi) * tanh2_q(pg);            \
                C2p = C2;                                                        \
                h2p = sig_p(po) * tanh_q(C2);                                    \
                sum2 += h2p;                                                     \
            }                                                                    \
        }                                                                        \
        _Pragma("unroll")                                                        \
        for (int ti = 0; ti < 2; ++ti) {                                         \
            if (ti < ntile) {                                                    \
                f32x4 a = accx[ti];                                              \
                a = __builtin_amdgcn_mfma_f32_16x16x32_bf16(wfrag[ti][1], bf1, a, 0, 0, 0); \
                a = __builtin_amdgcn_mfma_f32_16x16x32_bf16(wfrag[ti][2], bf2, a, 0, 0, 0); \
                float C = sig_p(a[1]) * C1[ti] + sig_p(a[0]) * tanh2_q(a[2]);    \
                C1[ti] = C;                                                      \
                float h = sig_p(a[3]) * tanh_q(C);                               \
                int unit = (tbase + ti) * 4 + (lane >> 4);                       \
                int k    = 32 + unit;                                            \
                int b    = lane & 15;                                            \
                vA[(P) ^ 1][(k >> 5) - 1][(((k >> 3) & 3) << 4) + b][k & 7] = f2bf(h); \
            }                                                                    \
        }                                                                        \
        if (isL2) {   /* MFMA only; save gates, chain runs next step */          \
            f32x4 a = l2binit;                                                   \
            a = __builtin_amdgcn_mfma_f32_16x16x32_bf16(l2frag[0], bf1, a, 0, 0, 0); \
            a = __builtin_amdgcn_mfma_f32_16x16x32_bf16(l2frag[1], bf2, a, 0, 0, 0); \
            aP = a;                                                              \
        }                                                                        \
        if (ntile > 0) { /* x-chunk MFMA for step tt+1 (x 2 barriers old) */     \
            const s16x8 bf0n = *(const s16x8*)&xS[XR][lane][0];                  \
            _Pragma("unroll")                                                    \
            for (int ti = 0; ti < 2; ++ti)                                       \
                if (ti < ntile)                                                  \
                    accx[ti] = __builtin_amdgcn_mfma_f32_16x16x32_bf16(wfrag[ti][0], bf0n, binit[ti], 0, 0, 0); \
        }                                                                        \
        __syncthreads();                                                         \
    }

    for (int t = 0; t < T_STEPS; t += 4) {
        STEP(t + 0, 0, 1, 2, rE)
        STEP(t + 1, 1, 2, 3, rO)
        STEP(t + 2, 0, 3, 0, rE)
        STEP(t + 3, 1, 0, 1, rO)
    }
#undef STEP

    // ---- drain: pending chain (h2_510), then final step (h2_511 from h1_511) ----
    if (isL2) {
        if (lane < 16) {
            float pi = aP[0] + whh2g[0] * h2p;
            float pf = aP[1] + whh2g[1] * h2p;
            float pg = aP[2] + whh2g[2] * h2p;
            float po = aP[3] + whh2g[3] * h2p;
            float C2 = sig_p(pf) * C2p + sig_p(pi) * tanh2_q(pg);
            C2p = C2;
            h2p = sig_p(po) * tanh_q(C2);
            sum2 += h2p;
        }
        s16x8 bf1 = *(const s16x8*)&vA[0][0][lane][0];
        s16x8 bf2 = *(const s16x8*)&vA[0][1][lane][0];
        f32x4 a = l2binit;
        a = __builtin_amdgcn_mfma_f32_16x16x32_bf16(l2frag[0], bf1, a, 0, 0, 0);
        a = __builtin_amdgcn_mfma_f32_16x16x32_bf16(l2frag[1], bf2, a, 0, 0, 0);
        if (lane < 16) {
            float pi = a[0] + whh2g[0] * h2p;
            float pf = a[1] + whh2g[1] * h2p;
            float pg = a[2] + whh2g[2] * h2p;
            float po = a[3] + whh2g[3] * h2p;
            float C2 = sig_p(pf) * C2p + sig_p(pi) * tanh2_q(pg);
            h2p = sig_p(po) * tanh_q(C2);
            sum2 += h2p;

            // ---- head: (lower, mu, upper, log_var) ----
            float agg = sum2 * (1.0f / 512.0f);
            float mu  = Wmu[0] * agg + bmu[0];
            float lv  = Wlv[0] * agg + blv[0];
            float sg  = __expf(0.5f * lv);
            int bg = bidx * 16 + lane;
            out[bg]             = mu - 1.96f * sg;
            out[B_TOT + bg]     = mu;
            out[2 * B_TOT + bg] = mu + 1.96f * sg;
            out[3 * B_TOT + bg] = lv;
        }
    }
}

extern "C" void kernel_launch(void* const* d_in, const int* in_sizes, int n_in,
                              void* d_out, int out_size, void* d_ws, size_t ws_size,
                              hipStream_t stream) {
    const float* x    = (const float*)d_in[0];
    const float* Wih1 = (const float*)d_in[1];
    const float* Whh1 = (const float*)d_in[2];
    const float* bih1 = (const float*)d_in[3];
    const float* bhh1 = (const float*)d_in[4];
    const float* Wih2 = (const float*)d_in[5];
    const float* Whh2 = (const float*)d_in[6];
    const float* bih2 = (const float*)d_in[7];
    const float* bhh2 = (const float*)d_in[8];
    const float* Wmu  = (const float*)d_in[9];
    const float* bmu  = (const float*)d_in[10];
    const float* Wlv  = (const float*)d_in[11];
    const float* blv  = (const float*)d_in[12];
    float* out = (float*)d_out;

    lstm_fused<<<dim3(B_TOT / 16), dim3(512), 0, stream>>>(
        x, Wih1, Whh1, bih1, bhh1, Wih2, Whh2, bih2, bhh2, Wmu, bmu, Wlv, blv, out);
}

// Round 6
// 428.539 us; speedup vs baseline: 1.0899x; 1.0899x over previous
//
#include <hip/hip_runtime.h>

#define B_TOT 4096
#define T_STEPS 512
#define IN 20
#define HID 51

typedef float f32x4 __attribute__((ext_vector_type(4)));
typedef short s16x8 __attribute__((ext_vector_type(8)));

__device__ __forceinline__ unsigned short f2bf(float f) {
    unsigned int u = __float_as_uint(f);
    unsigned int r = (u + 0x7fffu + ((u >> 16) & 1u)) >> 16;
    return (unsigned short)r;
}

#define L2E  1.4426950408889634f
#define L2E2 2.8853900817779268f

__device__ __forceinline__ float fast_rcp(float x) { return __builtin_amdgcn_rcpf(x); }
__device__ __forceinline__ float ex2(float x)      { return __builtin_amdgcn_exp2f(x); }
// sigma(x) where p = -x*log2(e) was folded into the weights
__device__ __forceinline__ float sig_p(float p)  { return fast_rcp(1.0f + ex2(p)); }
// tanh(x) where q = 2x*log2(e) was folded into the weights
__device__ __forceinline__ float tanh_q(float q) { return 1.0f - 2.0f * fast_rcp(1.0f + ex2(q)); }
// L2E2 * tanh(x), same folded argument — keeps cell state pre-scaled (C = L2E2*c)
__device__ __forceinline__ float tanh2_q(float q) {
    return __builtin_fmaf(fast_rcp(1.0f + ex2(q)), -2.0f * L2E2, L2E2);
}

// 16 waves (4 per SIMD), ONE tile per wave, 16 batches/block, grid = 256.
// r6: same total work as r4, 4x the latency hiding. Each wave's
// barrier-to-barrier serial path is a single tile (ds_read wait -> 2 MFMA ->
// one nonlin chain -> h write); 4 waves/SIMD interleave to fill the stalls
// that 2 waves/SIMD couldn't (r4: VALUBusy 42%, 740 stall-cy/SIMD/step).
//   w0..w12: L1 tile w
//   w13:     x stager (5 elems/lane, register-pipelined, quad-buffered xS)
//   w14:     L2 tile (rows 0..3 = Wih2 gates; K-chunks 1,2), chain inline (r4 style)
//   w15:     idle
// Kept from r4: x quad-buffer (stager writes x_{t+2}, loads x_{t+4} at step
// top -> no vmcnt drain at the barrier); accx precompute (x-chunk MFMA for
// step t+1 at bottom of step t); compile-time buffer indices via x4 unroll.
// Weights/biases pre-scaled by -log2e (i,f,o) / 2*log2e (g); cell state kept
// as C = 2*log2e*c so tanh_q(C) needs no mul in the dependent chain.

__global__ __launch_bounds__(1024)
void lstm_fused(const float* __restrict__ x,
                const float* __restrict__ Wih1, const float* __restrict__ Whh1,
                const float* __restrict__ bih1, const float* __restrict__ bhh1,
                const float* __restrict__ Wih2, const float* __restrict__ Whh2,
                const float* __restrict__ bih2, const float* __restrict__ bhh2,
                const float* __restrict__ Wmu,  const float* __restrict__ bmu,
                const float* __restrict__ Wlv,  const float* __restrict__ blv,
                float* __restrict__ out)
{
    // h staging: [buf][chunk(c=0:k32..63,c=1:k64..95)][(((k>>3)&3)<<4)|batch][k&7]
    __shared__ __align__(16) unsigned short vA[2][2][64][8];
    // x staging, quad-buffered: slot t%4 holds x_t fragments (rows 48..63 stay 0)
    __shared__ __align__(16) unsigned short xS[4][64][8];

    const int tid  = threadIdx.x;
    const int lane = tid & 63;
    const int w    = tid >> 6;      // 0..15
    const int bidx = blockIdx.x;

    const bool isT  = (w <= 12);    // L1 tile wave; tile index = w
    const bool isST = (w == 13);    // x stager
    const bool isL2 = (w == 14);    // layer-2 wave

    // ---- gather A-operand weight fragments: A[m=lane&15][k=(lane>>4)*8+j] ----
    s16x8 wfrag[3];
    f32x4 binit = {0.f, 0.f, 0.f, 0.f};
    {
        const int m = lane & 15;
        #pragma unroll
        for (int ks = 0; ks < 3; ++ks) {
            s16x8 f;
            #pragma unroll
            for (int j = 0; j < 8; ++j) {
                int k = ks * 32 + ((lane >> 4) << 3) + j;
                float v = 0.0f;
                if (isT) {
                    int g = m & 3, unit = w * 4 + (m >> 2);
                    if (unit < HID) {
                        int row = g * HID + unit;
                        if (k < IN) v = Wih1[row * IN + k];
                        else if (k >= 32 && k < 32 + HID) v = Whh1[row * HID + (k - 32)];
                        v *= (g == 2) ? L2E2 : -L2E;
                    }
                }
                f[j] = (short)f2bf(v);
            }
            wfrag[ks] = f;
        }
        if (isT) {
            int unit = w * 4 + (lane >> 4);
            if (unit < HID) {
                #pragma unroll
                for (int r = 0; r < 4; ++r)
                    binit[r] = (bih1[r * HID + unit] + bhh1[r * HID + unit]) * ((r == 2) ? L2E2 : -L2E);
            }
        }
    }

    // ---- h-write address (loop-invariant; pad unit 51 computes h=0 exactly) ----
    int hchunk = 0, hrow = 0, hj = 0;
    if (isT) {
        int unit = w * 4 + (lane >> 4);
        int k    = 32 + unit;
        hchunk = (k >> 5) - 1;
        hrow   = (((k >> 3) & 3) << 4) + (lane & 15);
        hj     = k & 7;
    }

    // ---- layer-2 tile fragments (w14): rows 0..3 = Wih2 gates, chunks 1,2 ----
    s16x8 l2frag[2];
    f32x4 l2binit = {0.f, 0.f, 0.f, 0.f};
    float whh2g[4] = {0.f, 0.f, 0.f, 0.f};
    if (isL2) {
        const int m = lane & 15;
        #pragma unroll
        for (int ks = 1; ks < 3; ++ks) {
            s16x8 f;
            #pragma unroll
            for (int j = 0; j < 8; ++j) {
                int k = ks * 32 + ((lane >> 4) << 3) + j;
                float v = 0.0f;
                if (m < 4 && k >= 32 && k < 32 + HID)
                    v = Wih2[m * HID + (k - 32)] * ((m == 2) ? L2E2 : -L2E);
                f[j] = (short)f2bf(v);
            }
            l2frag[ks - 1] = f;
        }
        #pragma unroll
        for (int r = 0; r < 4; ++r) {
            float s = (r == 2) ? L2E2 : -L2E;
            whh2g[r]   = Whh2[r] * s;
            l2binit[r] = (bih2[r] + bhh2[r]) * s;
        }
    }

    // ---- x stager setup (w13): 5 elems/lane, e = i*64+lane (320 total, no mask) ----
    const float* sp[5];
    int srow[5], sj[5];
    if (isST) {
        #pragma unroll
        for (int i = 0; i < 5; ++i) {
            int e = i * 64 + lane;
            int b = e / IN, m = e % IN;
            sp[i]   = x + ((size_t)(bidx * 16 + b) * T_STEPS) * IN + m;
            srow[i] = ((m >> 3) & 3) * 16 + b;
            sj[i]   = m & 7;
        }
    }

    // ---- zero-init staging buffers (pads must stay exact 0 forever) ----
    {
        unsigned short* vz = &vA[0][0][0][0];
        for (int i = tid; i < 2 * 2 * 64 * 8; i += 1024) vz[i] = 0;
        unsigned short* xz = &xS[0][0][0];
        for (int i = tid; i < 4 * 64 * 8; i += 1024) xz[i] = 0;
    }
    __syncthreads();
    float rE[5], rO[5];
    if (isST) {
        #pragma unroll
        for (int i = 0; i < 5; ++i) {
            xS[0][srow[i]][sj[i]] = f2bf(sp[i][0]);          // x_0
            xS[1][srow[i]][sj[i]] = f2bf(sp[i][IN]);         // x_1
            rE[i] = sp[i][(size_t)2 * IN];                   // x_2 (write at t=0)
            rO[i] = sp[i][(size_t)3 * IN];                   // x_3 (write at t=1)
        }
    }
    __syncthreads();

    // ---- precompute accx (x-chunk MFMA) for step 0 from xS[0] ----
    f32x4 accx = {0.f, 0.f, 0.f, 0.f};
    if (isT) {
        const s16x8 b00 = *(const s16x8*)&xS[0][lane][0];
        accx = __builtin_amdgcn_mfma_f32_16x16x32_bf16(wfrag[0], b00, binit, 0, 0, 0);
    }

    float C1t = 0.f;                // pre-scaled cell state: C = 2*log2e*c
    float C2p = 0.f, h2p = 0.f, sum2 = 0.f;

    // One timestep. P = tt&1 (h buffer), XR = (tt+1)%4 (x for next step),
    // XW = (tt+2)%4 (x slot written this step), XREG = rE (even tt) / rO (odd).
#define STEP(tt, P, XR, XW, XREG)                                                \
    {                                                                            \
        if (isST) {                                                              \
            const int t4 = ((tt) < T_STEPS - 4) ? (tt) + 4 : T_STEPS - 1;        \
            _Pragma("unroll")                                                    \
            for (int i = 0; i < 5; ++i) {                                        \
                xS[XW][srow[i]][sj[i]] = f2bf(XREG[i]);                          \
                XREG[i] = sp[i][(size_t)t4 * IN];                                \
            }                                                                    \
        }                                                                        \
        if (isT) {                                                               \
            const s16x8 bf1 = *(const s16x8*)&vA[P][0][lane][0];                 \
            const s16x8 bf2 = *(const s16x8*)&vA[P][1][lane][0];                 \
            f32x4 a = accx;                                                      \
            a = __builtin_amdgcn_mfma_f32_16x16x32_bf16(wfrag[1], bf1, a, 0, 0, 0); \
            a = __builtin_amdgcn_mfma_f32_16x16x32_bf16(wfrag[2], bf2, a, 0, 0, 0); \
            float C = sig_p(a[1]) * C1t + sig_p(a[0]) * tanh2_q(a[2]);           \
            C1t = C;                                                             \
            float h = sig_p(a[3]) * tanh_q(C);                                   \
            vA[(P) ^ 1][hchunk][hrow][hj] = f2bf(h);                             \
            const s16x8 bf0n = *(const s16x8*)&xS[XR][lane][0];                  \
            accx = __builtin_amdgcn_mfma_f32_16x16x32_bf16(wfrag[0], bf0n, binit, 0, 0, 0); \
        }                                                                        \
        if (isL2) {                                                              \
            const s16x8 bf1 = *(const s16x8*)&vA[P][0][lane][0];                 \
            const s16x8 bf2 = *(const s16x8*)&vA[P][1][lane][0];                 \
            f32x4 a = l2binit;                                                   \
            a = __builtin_amdgcn_mfma_f32_16x16x32_bf16(l2frag[0], bf1, a, 0, 0, 0); \
            a = __builtin_amdgcn_mfma_f32_16x16x32_bf16(l2frag[1], bf2, a, 0, 0, 0); \
            if ((tt) > 0 && lane < 16) {                                         \
                float pi = a[0] + whh2g[0] * h2p;                                \
                float pf = a[1] + whh2g[1] * h2p;                                \
                float pg = a[2] + whh2g[2] * h2p;                                \
                float po = a[3] + whh2g[3] * h2p;                                \
                float C2 = sig_p(pf) * C2p + sig_p(pi) * tanh2_q(pg);            \
                C2p = C2;                                                        \
                h2p = sig_p(po) * tanh_q(C2);                                    \
                sum2 += h2p;                                                     \
            }                                                                    \
        }                                                                        \
        __syncthreads();                                                         \
    }

    for (int t = 0; t < T_STEPS; t += 4) {
        STEP(t + 0, 0, 1, 2, rE)
        STEP(t + 1, 1, 2, 3, rO)
        STEP(t + 2, 0, 3, 0, rE)
        STEP(t + 3, 1, 0, 1, rO)
    }
#undef STEP

    // ---- final layer-2 step: h1_511 sits in vA[0] ----
    if (isL2) {
        s16x8 bf1 = *(const s16x8*)&vA[0][0][lane][0];
        s16x8 bf2 = *(const s16x8*)&vA[0][1][lane][0];
        f32x4 a = l2binit;
        a = __builtin_amdgcn_mfma_f32_16x16x32_bf16(l2frag[0], bf1, a, 0, 0, 0);
        a = __builtin_amdgcn_mfma_f32_16x16x32_bf16(l2frag[1], bf2, a, 0, 0, 0);
        if (lane < 16) {
            float pi = a[0] + whh2g[0] * h2p;
            float pf = a[1] + whh2g[1] * h2p;
            float pg = a[2] + whh2g[2] * h2p;
            float po = a[3] + whh2g[3] * h2p;
            float C2 = sig_p(pf) * C2p + sig_p(pi) * tanh2_q(pg);
            h2p = sig_p(po) * tanh_q(C2);
            sum2 += h2p;

            // ---- head: (lower, mu, upper, log_var) ----
            float agg = sum2 * (1.0f / 512.0f);
            float mu  = Wmu[0] * agg + bmu[0];
            float lv  = Wlv[0] * agg + blv[0];
            float sg  = __expf(0.5f * lv);
            int bg = bidx * 16 + lane;
            out[bg]             = mu - 1.96f * sg;
            out[B_TOT + bg]     = mu;
            out[2 * B_TOT + bg] = mu + 1.96f * sg;
            out[3 * B_TOT + bg] = lv;
        }
    }
}

extern "C" void kernel_launch(void* const* d_in, const int* in_sizes, int n_in,
                              void* d_out, int out_size, void* d_ws, size_t ws_size,
                              hipStream_t stream) {
    const float* x    = (const float*)d_in[0];
    const float* Wih1 = (const float*)d_in[1];
    const float* Whh1 = (const float*)d_in[2];
    const float* bih1 = (const float*)d_in[3];
    const float* bhh1 = (const float*)d_in[4];
    const float* Wih2 = (const float*)d_in[5];
    const float* Whh2 = (const float*)d_in[6];
    const float* bih2 = (const float*)d_in[7];
    const float* bhh2 = (const float*)d_in[8];
    const float* Wmu  = (const float*)d_in[9];
    const float* bmu  = (const float*)d_in[10];
    const float* Wlv  = (const float*)d_in[11];
    const float* blv  = (const float*)d_in[12];
    float* out = (float*)d_out;

    lstm_fused<<<dim3(B_TOT / 16), dim3(1024), 0, stream>>>(
        x, Wih1, Whh1, bih1, bhh1, Wih2, Whh2, bih2, bhh2, Wmu, bmu, Wlv, blv, out);
}